// Round 3
// baseline (177.023 us; speedup 1.0000x reference)
//
#include <hip/hip_runtime.h>
#include <cstdint>

// Problem constants: B=32, C=256, P=32, H=W=56
#define B_   32
#define C_   256
#define P_   32
#define HW_  3136
#define KT   64           // K-tile per staging round (2 MFMA k-steps)
#define NT64 49           // HW_/KT
#define KSPLIT_MAX 16

typedef __attribute__((ext_vector_type(8))) short  short8;   // 8 x bf16 (MFMA A/B frag)
typedef __attribute__((ext_vector_type(4))) float  floatx4;  // MFMA C/D frag

__device__ __forceinline__ unsigned short f2bf(float f) {
    // round-to-nearest-even f32 -> bf16
    union { float f; unsigned u; } v; v.f = f;
    unsigned r = v.u + 0x7fffu + ((v.u >> 16) & 1u);
    return (unsigned short)(r >> 16);
}

// ---------------------------------------------------------------------------
// Kernel 1: att[b,hw] = sigmoid( sum_p part[b,p,hw]*conv_w[p] + conv_b )
// 64-thread blocks (392 blocks) to spread the 12.9 MB read over >1.5 blocks/CU.
// ---------------------------------------------------------------------------
__global__ __launch_bounds__(64) void att_kernel(
    const float* __restrict__ part, const float* __restrict__ conv_w,
    const float* __restrict__ conv_b, float* __restrict__ att)
{
    const int HW4 = HW_ / 4;                          // 784
    int i4 = blockIdx.x * 64 + threadIdx.x;           // over B*HW/4 = 25088
    if (i4 >= B_ * HW4) return;
    int b  = i4 / HW4;
    int hw = (i4 - b * HW4) * 4;

    const float* pb = part + (size_t)b * P_ * HW_ + hw;
    float bias = conv_b[0];
    float4 z = make_float4(bias, bias, bias, bias);
#pragma unroll
    for (int p = 0; p < P_; ++p) {
        float w = conv_w[p];
        float4 v = *(const float4*)(pb + (size_t)p * HW_);
        z.x += v.x * w; z.y += v.y * w; z.z += v.z * w; z.w += v.w * w;
    }
    float4 s;
    s.x = 1.0f / (1.0f + __expf(-z.x));
    s.y = 1.0f / (1.0f + __expf(-z.y));
    s.z = 1.0f / (1.0f + __expf(-z.z));
    s.w = 1.0f / (1.0f + __expf(-z.w));
    *(float4*)(att + (size_t)b * HW_ + hw) = s;
}

// ---------------------------------------------------------------------------
// Kernel 2: batched bf16-MFMA GEMM, feats[b,p,c] = sum_k part[b,p,k]*x[b,c,k]*att[b,k]
// 512 threads (8 waves). Tile M=32(all p) x N=256(all c) x KT=64. K-split.
// Next-round global loads issued between the two barriers -> stay in flight
// during MFMA + far barrier (MLP). Wave w owns c in [w*32, w*32+32).
// LDS stride 72 halves = 144 B = 36 banks: frag-read bank base (4*(row+qd))%32
// -> 8 lanes per 4-bank group = matches the 8 inherent b128 phases (conflict-free).
// ---------------------------------------------------------------------------
__global__ __launch_bounds__(512, 4) void gemm_mfma(
    const float* __restrict__ x,        // [B,C,HW]
    const float* __restrict__ part,     // [B,P,HW]
    const float* __restrict__ att,      // [B,HW]
    float* __restrict__ partial,        // [ksplit, B, P, C]
    int ksplit)
{
    __shared__ __align__(16) unsigned short Abf[P_][KT + 8];   // 32 x 72 = 4,608 B
    __shared__ __align__(16) unsigned short Bbf[C_][KT + 8];   // 256x 72 = 36,864 B

    const int b  = blockIdx.y;
    const int kc = blockIdx.x;
    const int t0 = kc * NT64 / ksplit;
    const int t1 = (kc + 1) * NT64 / ksplit;

    const int tid  = threadIdx.x;
    const int lane = tid & 63;
    const int wv   = tid >> 6;        // wave 0..7 -> c range [wv*32, wv*32+32)
    const int qd   = lane >> 4;       // quad 0..3
    const int r15  = lane & 15;

    // staging map: A: (p = tid>>4, k4); B: 8 rows c = l*32 + (tid>>4), same k4
    const int sr = tid >> 4;          // 0..31
    const int k4 = (tid & 15) << 2;   // 0,4,...,60

    const float* xb = x    + (size_t)b * C_ * HW_;
    const float* pb = part + (size_t)b * P_ * HW_ + (size_t)sr * HW_ + k4;
    const float* ab = att  + (size_t)b * HW_ + k4;

    floatx4 acc[2][2];
#pragma unroll
    for (int mt = 0; mt < 2; ++mt)
#pragma unroll
        for (int nt = 0; nt < 2; ++nt) acc[mt][nt] = (floatx4)0.0f;

    float4 pv, av, xv[8];
    {   // prefetch round t0
        const int kb = t0 * KT;
        pv = *(const float4*)(pb + kb);
        av = *(const float4*)(ab + kb);
#pragma unroll
        for (int l = 0; l < 8; ++l)
            xv[l] = *(const float4*)(xb + (size_t)((l << 5) + sr) * HW_ + kb + k4);
    }

    for (int t = t0; t < t1; ++t) {
        // ---- stage from prefetched regs ----
        {
            ushort4 a4;
            a4.x = f2bf(pv.x); a4.y = f2bf(pv.y); a4.z = f2bf(pv.z); a4.w = f2bf(pv.w);
            *(ushort4*)&Abf[sr][k4] = a4;
        }
#pragma unroll
        for (int l = 0; l < 8; ++l) {
            ushort4 b4;
            b4.x = f2bf(xv[l].x * av.x); b4.y = f2bf(xv[l].y * av.y);
            b4.z = f2bf(xv[l].z * av.z); b4.w = f2bf(xv[l].w * av.w);
            *(ushort4*)&Bbf[(l << 5) + sr][k4] = b4;
        }
        __syncthreads();   // tiles ready

        // ---- issue next round's loads NOW (in flight across MFMA + barrier) ----
        if (t + 1 < t1) {
            const int kb = (t + 1) * KT;
            pv = *(const float4*)(pb + kb);
            av = *(const float4*)(ab + kb);
#pragma unroll
            for (int l = 0; l < 8; ++l)
                xv[l] = *(const float4*)(xb + (size_t)((l << 5) + sr) * HW_ + kb + k4);
        }

        // ---- MFMA: 2 k-steps x (2 mt x 2 nt) ----
#pragma unroll
        for (int ks = 0; ks < 2; ++ks) {
            const int ko = ks * 32 + qd * 8;
            short8 af0 = *(const short8*)&Abf[r15][ko];
            short8 af1 = *(const short8*)&Abf[16 + r15][ko];
            short8 bf0 = *(const short8*)&Bbf[(wv << 5) + r15][ko];
            short8 bf1 = *(const short8*)&Bbf[(wv << 5) + 16 + r15][ko];
            acc[0][0] = __builtin_amdgcn_mfma_f32_16x16x32_bf16(af0, bf0, acc[0][0], 0, 0, 0);
            acc[0][1] = __builtin_amdgcn_mfma_f32_16x16x32_bf16(af0, bf1, acc[0][1], 0, 0, 0);
            acc[1][0] = __builtin_amdgcn_mfma_f32_16x16x32_bf16(af1, bf0, acc[1][0], 0, 0, 0);
            acc[1][1] = __builtin_amdgcn_mfma_f32_16x16x32_bf16(af1, bf1, acc[1][1], 0, 0, 0);
        }
        __syncthreads();   // LDS free for next round's staging
    }

    // ---- epilogue: plain stores of K-split partials ----
    // D layout: row(m=p) = qd*4 + reg, col(n=c within 16-tile) = r15
    float* ob = partial + ((size_t)kc * B_ + b) * (P_ * C_);
#pragma unroll
    for (int mt = 0; mt < 2; ++mt) {
#pragma unroll
        for (int nt = 0; nt < 2; ++nt) {
#pragma unroll
            for (int rg = 0; rg < 4; ++rg) {
                int p = mt * 16 + qd * 4 + rg;
                int c = (wv << 5) + nt * 16 + r15;
                ob[p * C_ + c] = acc[mt][nt][rg];
            }
        }
    }
}

// ---------------------------------------------------------------------------
// Stage 3: out[i] = sum_kc partial[kc][i].  float4 over 262144 floats.
// ---------------------------------------------------------------------------
__global__ __launch_bounds__(256) void reduce_k(
    const float* __restrict__ partial, float* __restrict__ out, int ksplit)
{
    int i = blockIdx.x * 256 + threadIdx.x;       // over 65536 float4s
    const float4* p4 = (const float4*)partial;
    float4 s = p4[i];
    for (int kc = 1; kc < ksplit; ++kc) {
        float4 v = p4[(size_t)kc * (B_ * P_ * C_ / 4) + i];
        s.x += v.x; s.y += v.y; s.z += v.z; s.w += v.w;
    }
    ((float4*)out)[i] = s;
}

extern "C" void kernel_launch(void* const* d_in, const int* in_sizes, int n_in,
                              void* d_out, int out_size, void* d_ws, size_t ws_size,
                              hipStream_t stream) {
    const float* x      = (const float*)d_in[0];
    const float* part   = (const float*)d_in[1];
    const float* conv_w = (const float*)d_in[2];
    const float* conv_b = (const float*)d_in[3];

    // ws layout: [0, 2MB) att ; [2MB, ...) K-split partials
    const size_t ATT_OFF = 2u << 20;
    float* att = (float*)d_ws;
    const size_t slab = (size_t)B_ * P_ * C_ * 4;   // 1 MiB per split
    int ksplit = (ws_size > ATT_OFF) ? (int)((ws_size - ATT_OFF) / slab) : 1;
    if (ksplit > KSPLIT_MAX) ksplit = KSPLIT_MAX;
    if (ksplit < 1) ksplit = 1;
    float* partial = (ksplit > 1) ? (float*)((char*)d_ws + ATT_OFF) : (float*)d_out;

    att_kernel<<<dim3((B_ * (HW_ / 4) + 63) / 64), dim3(64), 0, stream>>>(
        part, conv_w, conv_b, att);

    gemm_mfma<<<dim3(ksplit, B_), dim3(512), 0, stream>>>(
        x, part, att, partial, ksplit);

    if (ksplit > 1) {
        reduce_k<<<dim3((B_ * P_ * C_ / 4) / 256), dim3(256), 0, stream>>>(
            partial, (float*)d_out, ksplit);
    }
}